// Round 5
// baseline (380.277 us; speedup 1.0000x reference)
//
#include <hip/hip_runtime.h>
#include <hip/hip_bf16.h>
#include <math.h>

#define F_IN 256
#define F_OUT 64
#define NEG_SLOPE 0.2f
#define SHIFT 7
#define NPB 128            // nodes per bucket
#define MAXK 1024          // max buckets (N <= 131072, matches 17-bit j pack)
#define CAP 4608           // LDS staging records/bucket (mean 4096, +8 sigma)
#define OVF 4              // per-thread overflow regs (+1024 records headroom)
#define GRID_B 256         // blocks for count/bin (ranges must match)

__device__ __forceinline__ float bf2f(__hip_bfloat16 v) {
    return __bfloat162float(v);
}

typedef short short8 __attribute__((ext_vector_type(8)));
typedef float f32x4 __attribute__((ext_vector_type(4)));

// RNE float->bf16 bits (finite inputs)
__device__ __forceinline__ unsigned int bf16_bits(float v) {
    unsigned int u = __float_as_uint(v);
    return (u + 0x7fffu + ((u >> 16) & 1u)) >> 16;
}

// ---------------------------------------------------------------------------
// MFMA GEMM: h16 = bf16(x @ W) [PERMUTED layout], a_src = h@att_src,
// a_dst = h@att_dst.  bf16x3 split (xh*Wh + xl*Wh + xh*Wl) ~ fp32 accuracy.
//
// v4 (verified R4): depth-2 software pipeline in q (only cur/nxt float4 pairs
// live, sched_barrier(0) pins it) -> no scratch spill. (512,2): 16 waves/CU,
// VGPR 128, LDS 64 KB. h16 stored PERMUTED (phys fr*4+c = logical c*16+fr):
// 8-B/lane stores, 4 full 128-B rows per instruction.
// ---------------------------------------------------------------------------
#define WHI(q, c, l) (((((q)*4 + (c)) * 64) + (l)) * 8)
#define WLO(q, c, l) (16384 + WHI(q, c, l))

__global__ __launch_bounds__(512, 2) void gemm_kernel(
    const float* __restrict__ x, const float* __restrict__ W,
    const float* __restrict__ att_src, const float* __restrict__ att_dst,
    __hip_bfloat16* __restrict__ h16, float* __restrict__ a_src,
    float* __restrict__ a_dst, int N, int nTiles)
{
    __shared__ unsigned short sW[32768];   // [hi|lo][q][c][lane][e] = 64 KB

    const int t = threadIdx.x;
    const int lane = t & 63;
    const int w = t >> 6;          // wave id (0..7)
    const int g = lane >> 4;       // k-block group (0..3)
    const int fr = lane & 15;      // A-row / B-col / D-col within fragment

    // ---- stage W as hi/lo bf16 fragments (once per block) ----
    for (int idx = t; idx < 2048; idx += 512) {
        const int q = idx >> 8;
        const int c = (idx >> 6) & 3;
        const int l = idx & 63;
        const int col = c * 16 + (l & 15);
        const float* wp = W + (size_t)(q * 32 + ((l >> 4) * 8)) * F_OUT + col;
        short8 hv, lv;
#pragma unroll
        for (int e = 0; e < 8; e++) {
            float wv = wp[(size_t)e * F_OUT];
            unsigned int hb = bf16_bits(wv);
            float hf = __uint_as_float(hb << 16);
            unsigned int lb = bf16_bits(wv - hf);
            hv[e] = (short)hb;
            lv[e] = (short)lb;
        }
        *(short8*)&sW[WHI(q, c, l)] = hv;
        *(short8*)&sW[WLO(q, c, l)] = lv;
    }
    __syncthreads();

    // per-lane attention weight slices (4 cols each, cached)
    float as4[4], ad4[4];
#pragma unroll
    for (int c = 0; c < 4; c++) {
        as4[c] = att_src[c * 16 + fr];
        ad4[c] = att_dst[c * 16 + fr];
    }

    const float4 z4 = make_float4(0.f, 0.f, 0.f, 0.f);

    for (int tile = blockIdx.x; tile < nTiles; tile += gridDim.x) {
        const int R0 = tile * 128 + w * 16;
        const int rowA = R0 + fr;
        const bool okA = rowA < N;
        const float* xrow = x + (size_t)rowA * F_IN + g * 8;

        f32x4 acc[4];
#pragma unroll
        for (int c = 0; c < 4; c++) acc[c] = (f32x4){0.f, 0.f, 0.f, 0.f};

        // depth-2 pipeline: only 4 float4 of x live at any time
        float4 cur0 = okA ? *(const float4*)(xrow + 0) : z4;
        float4 cur1 = okA ? *(const float4*)(xrow + 4) : z4;

#pragma unroll
        for (int q = 0; q < 8; q++) {
            float4 nxt0 = z4, nxt1 = z4;
            if (q < 7) {
                nxt0 = okA ? *(const float4*)(xrow + (q + 1) * 32)     : z4;
                nxt1 = okA ? *(const float4*)(xrow + (q + 1) * 32 + 4) : z4;
            }

            const float vf[8] = {cur0.x, cur0.y, cur0.z, cur0.w,
                                 cur1.x, cur1.y, cur1.z, cur1.w};
            short8 ahi, alo;
#pragma unroll
            for (int e = 0; e < 8; e++) {
                unsigned int hb = bf16_bits(vf[e]);
                float hf = __uint_as_float(hb << 16);
                unsigned int lb = bf16_bits(vf[e] - hf);
                ahi[e] = (short)hb;
                alo[e] = (short)lb;
            }
#pragma unroll
            for (int c = 0; c < 4; c++) {
                short8 bh = *(const short8*)&sW[WHI(q, c, lane)];
                short8 bl = *(const short8*)&sW[WLO(q, c, lane)];
                acc[c] = __builtin_amdgcn_mfma_f32_16x16x32_bf16(ahi, bh, acc[c], 0, 0, 0);
                acc[c] = __builtin_amdgcn_mfma_f32_16x16x32_bf16(alo, bh, acc[c], 0, 0, 0);
                acc[c] = __builtin_amdgcn_mfma_f32_16x16x32_bf16(ahi, bl, acc[c], 0, 0, 0);
            }
            cur0 = nxt0;
            cur1 = nxt1;
            __builtin_amdgcn_sched_barrier(0);   // pin pipeline depth (no re-hoist)
        }

        // ---- epilogue: a_src/a_dst partials ----
        float sr[4] = {0.f, 0.f, 0.f, 0.f};
        float sd[4] = {0.f, 0.f, 0.f, 0.f};
#pragma unroll
        for (int c = 0; c < 4; c++) {
#pragma unroll
            for (int r = 0; r < 4; r++) {
                float v = acc[c][r];
                sr[r] = fmaf(v, as4[c], sr[r]);
                sd[r] = fmaf(v, ad4[c], sd[r]);
            }
        }
#pragma unroll
        for (int off = 1; off <= 8; off <<= 1) {
#pragma unroll
            for (int r = 0; r < 4; r++) {
                sr[r] += __shfl_xor(sr[r], off, 64);
                sd[r] += __shfl_xor(sd[r], off, 64);
            }
        }

        // ---- h16 store: permuted layout, 8 B/lane, 4 full rows / instr ----
#pragma unroll
        for (int r = 0; r < 4; r++) {
            const int row = R0 + g * 4 + r;
            if (row < N) {
                unsigned int lo = bf16_bits(acc[0][r]) | (bf16_bits(acc[1][r]) << 16);
                unsigned int hi = bf16_bits(acc[2][r]) | (bf16_bits(acc[3][r]) << 16);
                *(int2*)(h16 + (size_t)row * F_OUT + fr * 4) = make_int2((int)lo, (int)hi);
            }
        }

        if (fr < 4) {
            const int row = R0 + g * 4 + fr;
            if (row < N) {
                float vs = (fr == 0) ? sr[0] : (fr == 1) ? sr[1] : (fr == 2) ? sr[2] : sr[3];
                float vd = (fr == 0) ? sd[0] : (fr == 1) ? sd[1] : (fr == 2) ? sd[2] : sd[3];
                a_src[row] = vs;
                a_dst[row] = vd;
            }
        }
    }
}

// ---------------------------------------------------------------------------
// Count: per-block LDS bucket histogram -> pbh[block][K] (no global atomics).
// ---------------------------------------------------------------------------
__global__ __launch_bounds__(1024) void bucket_count_kernel(
    const int* __restrict__ dst, int* __restrict__ pbh, int E, int K, int R)
{
    __shared__ int s[MAXK];
    const int t = threadIdx.x;
    for (int b = t; b < K; b += 1024) s[b] = 0;
    __syncthreads();
    const int start = blockIdx.x * R;
    const int end = min(E, start + R);
    for (int e = start + t * 4; e < end; e += 4096) {
        if (e + 3 < end) {
            int4 d = *(const int4*)&dst[e];
            atomicAdd(&s[d.x >> SHIFT], 1);
            atomicAdd(&s[d.y >> SHIFT], 1);
            atomicAdd(&s[d.z >> SHIFT], 1);
            atomicAdd(&s[d.w >> SHIFT], 1);
        } else {
            for (int q = e; q < end; q++) atomicAdd(&s[dst[q] >> SHIFT], 1);
        }
    }
    __syncthreads();
    int* row = pbh + (size_t)blockIdx.x * K;
    for (int b = t; b < K; b += 1024) row[b] = s[b];
}

// ---------------------------------------------------------------------------
// Column scan: one wave per bucket k. 64 lanes scan the 256 per-block counts
// in 4 chunks (wave shfl-scan + carry) -> cbase[block][k] (exclusive, base 0)
// and per-bucket total btot[k]. Fully parallel across 782 blocks.
// ---------------------------------------------------------------------------
__global__ __launch_bounds__(64) void colscan_kernel(
    const int* __restrict__ pbh, int* __restrict__ cbase,
    int* __restrict__ btot, int K, int NBLK)
{
    const int k = blockIdx.x;
    const int lane = threadIdx.x;
    // prefetch all chunks (NBLK <= 256 -> 4 chunks)
    int v[4];
#pragma unroll
    for (int c = 0; c < 4; c++) {
        int b = c * 64 + lane;
        v[c] = (b < NBLK) ? pbh[(size_t)b * K + k] : 0;
    }
    int carry = 0;
#pragma unroll
    for (int c = 0; c < 4; c++) {
        int orig = v[c];
        int s = v[c];
#pragma unroll
        for (int off = 1; off < 64; off <<= 1) {
            int u = __shfl_up(s, off, 64);
            if (lane >= off) s += u;
        }
        int b = c * 64 + lane;
        if (b < NBLK) cbase[(size_t)b * K + k] = carry + s - orig;  // exclusive
        carry += __shfl(s, 63, 64);
    }
    if (lane == 0) btot[k] = carry;
}

// ---------------------------------------------------------------------------
// Bucket base scan: exclusive scan of btot -> bbase (K <= 1024, one block).
// ---------------------------------------------------------------------------
__global__ __launch_bounds__(1024) void bbase_scan_kernel(
    const int* __restrict__ btot, int* __restrict__ bbase, int K, int E)
{
    __shared__ int s[1024];
    const int t = threadIdx.x;
    int v = (t < K) ? btot[t] : 0;
    s[t] = v;
    __syncthreads();
    for (int off = 1; off < 1024; off <<= 1) {
        int u = (t >= off) ? s[t - off] : 0;
        __syncthreads();
        s[t] += u;
        __syncthreads();
    }
    if (t < K) bbase[t] = s[t] - v;       // exclusive
    if (t == 0) bbase[K] = E;
}

// ---------------------------------------------------------------------------
// Bin: single sweep. LDS cursors = bbase[b] + this block's chunk base;
// per edge: one LDS atomic + one 4-B write into the block's ~50 KB window.
// Record = j | local_i << 17 (p recomputed in node_kernel).
// ---------------------------------------------------------------------------
__global__ __launch_bounds__(1024) void bin_kernel(
    const int* __restrict__ ei, const int* __restrict__ cbase,
    const int* __restrict__ bbase, int* __restrict__ rec, int E, int K, int R)
{
    __shared__ int cb[MAXK];
    const int t = threadIdx.x;
    const int start = blockIdx.x * R;
    const int end = min(E, start + R);
    const int* crow = cbase + (size_t)blockIdx.x * K;
    for (int b = t; b < K; b += 1024) cb[b] = bbase[b] + crow[b];
    __syncthreads();

    for (int e = start + t * 4; e < end; e += 4096) {
        if (e + 3 < end) {
            int4 jj = *(const int4*)&ei[e];
            int4 ii = *(const int4*)&ei[E + e];
            int p0 = atomicAdd(&cb[ii.x >> SHIFT], 1);
            int p1 = atomicAdd(&cb[ii.y >> SHIFT], 1);
            int p2 = atomicAdd(&cb[ii.z >> SHIFT], 1);
            int p3 = atomicAdd(&cb[ii.w >> SHIFT], 1);
            rec[p0] = jj.x | ((ii.x & (NPB - 1)) << 17);
            rec[p1] = jj.y | ((ii.y & (NPB - 1)) << 17);
            rec[p2] = jj.z | ((ii.z & (NPB - 1)) << 17);
            rec[p3] = jj.w | ((ii.w & (NPB - 1)) << 17);
        } else {
            for (int q = e; q < end; q++) {
                int j = ei[q], i = ei[E + q];
                int pos = atomicAdd(&cb[i >> SHIFT], 1);
                rec[pos] = j | ((i & (NPB - 1)) << 17);
            }
        }
    }
}

// ---------------------------------------------------------------------------
// Sort: one block per bucket; stage 4-B records in LDS (+overflow regs),
// count 128 local degrees, block-scan, in-place ordered write-back + row_ptr.
// ---------------------------------------------------------------------------
__global__ __launch_bounds__(256) void sort_kernel(
    int* __restrict__ rec, const int* __restrict__ bbase,
    int* __restrict__ row_ptr, int N, int E, int K)
{
    __shared__ int stage[CAP];
    __shared__ int deg[NPB];
    __shared__ int sval[NPB];
    __shared__ int base[NPB];
    __shared__ int cnt[NPB];
    const int t = threadIdx.x;
    const int b = blockIdx.x;
    const int s = bbase[b], e = bbase[b + 1];
    const int tot = e - s;
    const int nodeBase = b << SHIFT;
    const int nodes = min(NPB, N - nodeBase);

    if (t < NPB) deg[t] = 0;
    __syncthreads();

    int ovf[OVF];
    for (int r = t; r < tot; r += 256) {
        int m = rec[s + r];
        if (r < CAP) stage[r] = m;
        else { int k = (r - CAP) >> 8; if (k < OVF) ovf[k] = m; }
        atomicAdd(&deg[(m >> 17) & (NPB - 1)], 1);
    }
    __syncthreads();

    if (t < NPB) sval[t] = deg[t];
    __syncthreads();
    for (int off = 1; off < NPB; off <<= 1) {
        int v = (t < NPB && t >= off) ? sval[t - off] : 0;
        __syncthreads();
        if (t < NPB) sval[t] += v;
        __syncthreads();
    }
    if (t < NPB) {
        base[t] = sval[t] - deg[t];              // exclusive
        cnt[t] = 0;
        if (t < nodes) row_ptr[nodeBase + t] = s + base[t];
    }
    if (b == K - 1 && t == 0) row_ptr[N] = E;
    __syncthreads();

    for (int r = t; r < tot; r += 256) {
        int m = (r < CAP) ? stage[r] : ovf[(r - CAP) >> 8];
        int li = (m >> 17) & (NPB - 1);
        int rk = atomicAdd(&cnt[li], 1);
        rec[s + base[li] + rk] = m;              // 16-KB window, L2-combined
    }
}

// ---------------------------------------------------------------------------
// Node aggregation v2: one wave/node, lane=EDGE for softmax (one exp/64
// edges), lane=feature for the h accumulate.
// Latency-chain fixes (post-mortem R4: 120 us, latency-bound at 20% HBM):
//  - h16 gathers for first 16 edges issue CONCURRENTLY with the a_src[j]
//    scattered gather (both depend only on rec; vmcnt in-order lets the
//    p-compute wait on a_src while 16 h16 loads stay in flight).
//  - depth-2 pipelined fma loop: issue group u+16 before fma of group u;
//    raw ushort staging defers bf16->f32 cvt to the fma.
//  - no scalar tail: slots >= cnt broadcast j=0/p=0 -> all hit h16 row 0
//    (one hot line, free) and fma x0.
// h16 is PERMUTED (phys fr*4+c = logical c*16+fr): lane reads via pcol.
// ---------------------------------------------------------------------------
__global__ __launch_bounds__(256) void node_kernel(
    const __hip_bfloat16* __restrict__ h16, const float* __restrict__ a_src,
    const float* __restrict__ a_dst, const int* __restrict__ row_ptr,
    const int* __restrict__ rec, const float* __restrict__ bias,
    float* __restrict__ out, int N)
{
    const int w = threadIdx.x >> 6;
    const int lane = threadIdx.x & 63;
    const int i = blockIdx.x * 4 + w;
    if (i >= N) return;

    const int pcol = ((lane & 15) << 2) | (lane >> 4);   // phys pos of logical col=lane
    const unsigned short* __restrict__ hp = (const unsigned short*)h16 + pcol;

    const int s = row_ptr[i];
    const int e = row_ptr[i + 1];

    const float adst_i = a_dst[i];
    float vs = a_src[i] + adst_i;
    vs = fmaxf(vs, NEG_SLOPE * vs);              // LeakyReLU(0.2)
    const float pself = __expf(vs);
    float denl = (lane == 0) ? pself : 0.f;      // per-lane den partials
    float acc = pself * __uint_as_float((unsigned int)hp[(size_t)i * F_OUT] << 16);

    for (int k = s; k < e; k += 64) {
        const int cnt = min(64, e - k);
        int r = (lane < cnt) ? rec[k + lane] : 0;      // coalesced
        int j = r & 0x1FFFF;

        // round trip A: scattered a_src gather (issued immediately)
        float asj = a_src[j];

        // round trip B (concurrent with A): prefetch h16 for edges 0..15
        unsigned short ga[8], gb[8];
#pragma unroll
        for (int c = 0; c < 8; c++) {
            int jc = __shfl(j, c, 64);
            ga[c] = hp[(size_t)jc * F_OUT];
        }
#pragma unroll
        for (int c = 0; c < 8; c++) {
            int jc = __shfl(j, 8 + c, 64);
            gb[c] = hp[(size_t)jc * F_OUT];
        }

        // p-compute (waits only on asj; h16 loads stay in flight)
        float v = asj + adst_i;
        v = fmaxf(v, NEG_SLOPE * v);
        float p = __expf(v);                           // ONE exp / 64 edges
        if (lane >= cnt) p = 0.f;
        denl += p;

        // depth-2 pipelined gather+fma over groups of 8
        for (int u = 0; u < cnt; u += 8) {
            unsigned short gc[8];
            const bool more = (u + 16) < cnt;
            if (more) {
#pragma unroll
                for (int c = 0; c < 8; c++) {
                    int jc = __shfl(j, u + 16 + c, 64);
                    gc[c] = hp[(size_t)jc * F_OUT];
                }
            } else {
#pragma unroll
                for (int c = 0; c < 8; c++) gc[c] = 0;
            }
#pragma unroll
            for (int c = 0; c < 8; c++) {
                float pc = __shfl(p, u + c, 64);
                acc = fmaf(pc, __uint_as_float((unsigned int)ga[c] << 16), acc);
            }
#pragma unroll
            for (int c = 0; c < 8; c++) { ga[c] = gb[c]; gb[c] = gc[c]; }
        }
    }

    float den = denl;
#pragma unroll
    for (int o = 32; o > 0; o >>= 1) den += __shfl_xor(den, o, 64);

    out[(size_t)i * F_OUT + lane] = acc / (den + 1e-16f) + bias[lane];
}

// ---------------------------------------------------------------------------
extern "C" void kernel_launch(void* const* d_in, const int* in_sizes, int n_in,
                              void* d_out, int out_size, void* d_ws, size_t ws_size,
                              hipStream_t stream)
{
    const float* x      = (const float*)d_in[0];
    const int*   ei     = (const int*)d_in[1];
    const float* W      = (const float*)d_in[2];
    const float* att_sr = (const float*)d_in[3];
    const float* att_ds = (const float*)d_in[4];
    const float* bias   = (const float*)d_in[5];
    float* out = (float*)d_out;

    const int N = in_sizes[0] / F_IN;
    const int E = in_sizes[1] / 2;
    const int K = (N + NPB - 1) >> SHIFT;   // 782 for N=100000
    const int R = (((E + GRID_B - 1) / GRID_B) + 3) & ~3;   // per-block range, x4

    char* ws = (char*)d_ws;
    size_t off = 0;
    auto alloc = [&](size_t bytes) -> void* {
        void* p = ws + off;
        off = (off + bytes + 255) & ~(size_t)255;
        return p;
    };
    __hip_bfloat16* h16 = (__hip_bfloat16*)alloc((size_t)N * F_OUT * 2);
    float* a_src   = (float*)alloc((size_t)N * 4);
    float* a_dst   = (float*)alloc((size_t)N * 4);
    int*   pbh     = (int*)alloc((size_t)GRID_B * K * 4);
    int*   cbase   = (int*)alloc((size_t)GRID_B * K * 4);
    int*   btot    = (int*)alloc((size_t)K * 4);
    int*   bbase   = (int*)alloc((size_t)(K + 1) * 4);
    int*   row_ptr = (int*)alloc((size_t)(N + 1) * 4);
    int*   rec     = (int*)alloc((size_t)E * 4);
    (void)ws_size; (void)n_in; (void)out_size;

    const int nTiles = (N + 127) >> 7;                      // 128-row tiles
    const int gemmGrid = nTiles < 512 ? nTiles : 512;       // 2 blocks/CU

    gemm_kernel<<<gemmGrid, 512, 0, stream>>>(x, W, att_sr, att_ds, h16, a_src, a_dst, N, nTiles);
    bucket_count_kernel<<<GRID_B, 1024, 0, stream>>>(ei + E, pbh, E, K, R);
    colscan_kernel<<<K, 64, 0, stream>>>(pbh, cbase, btot, K, GRID_B);
    bbase_scan_kernel<<<1, 1024, 0, stream>>>(btot, bbase, K, E);
    bin_kernel<<<GRID_B, 1024, 0, stream>>>(ei, cbase, bbase, rec, E, K, R);
    sort_kernel<<<K, 256, 0, stream>>>(rec, bbase, row_ptr, N, E, K);
    node_kernel<<<(N + 3) / 4, 256, 0, stream>>>(h16, a_src, a_dst, row_ptr, rec, bias, out, N);
}

// Round 6
// 331.163 us; speedup vs baseline: 1.1483x; 1.1483x over previous
//
#include <hip/hip_runtime.h>
#include <hip/hip_bf16.h>
#include <math.h>

#define F_IN 256
#define F_OUT 64
#define NEG_SLOPE 0.2f
#define SHIFT 7
#define NPB 128            // nodes per bucket
#define MAXK 1024          // max buckets (N <= 131072, matches 17-bit j pack)
#define CAP 4608           // LDS staging records/bucket (mean 4096, +8 sigma)
#define OVF 4              // per-thread overflow regs (+1024 records headroom)
#define GRID_B 256         // blocks for count/bin (ranges must match)

__device__ __forceinline__ float bf2f(__hip_bfloat16 v) {
    return __bfloat162float(v);
}

typedef short short8 __attribute__((ext_vector_type(8)));
typedef float f32x4 __attribute__((ext_vector_type(4)));

// RNE float->bf16 bits (finite inputs)
__device__ __forceinline__ unsigned int bf16_bits(float v) {
    unsigned int u = __float_as_uint(v);
    return (u + 0x7fffu + ((u >> 16) & 1u)) >> 16;
}

// ---------------------------------------------------------------------------
// MFMA GEMM: h16 = bf16(x @ W) [PERMUTED layout], a_src = h@att_src,
// a_dst = h@att_dst.  bf16x3 split (xh*Wh + xl*Wh + xh*Wl) ~ fp32 accuracy.
//
// v4 (verified R4): depth-2 software pipeline in q (only cur/nxt float4 pairs
// live, sched_barrier(0) pins it) -> no scratch spill. (512,2): 16 waves/CU,
// VGPR 128, LDS 64 KB. h16 stored PERMUTED (phys fr*4+c = logical c*16+fr):
// 8-B/lane stores, 4 full 128-B rows per instruction.
// ---------------------------------------------------------------------------
#define WHI(q, c, l) (((((q)*4 + (c)) * 64) + (l)) * 8)
#define WLO(q, c, l) (16384 + WHI(q, c, l))

__global__ __launch_bounds__(512, 2) void gemm_kernel(
    const float* __restrict__ x, const float* __restrict__ W,
    const float* __restrict__ att_src, const float* __restrict__ att_dst,
    __hip_bfloat16* __restrict__ h16, float* __restrict__ a_src,
    float* __restrict__ a_dst, int N, int nTiles)
{
    __shared__ unsigned short sW[32768];   // [hi|lo][q][c][lane][e] = 64 KB

    const int t = threadIdx.x;
    const int lane = t & 63;
    const int w = t >> 6;          // wave id (0..7)
    const int g = lane >> 4;       // k-block group (0..3)
    const int fr = lane & 15;      // A-row / B-col / D-col within fragment

    // ---- stage W as hi/lo bf16 fragments (once per block) ----
    for (int idx = t; idx < 2048; idx += 512) {
        const int q = idx >> 8;
        const int c = (idx >> 6) & 3;
        const int l = idx & 63;
        const int col = c * 16 + (l & 15);
        const float* wp = W + (size_t)(q * 32 + ((l >> 4) * 8)) * F_OUT + col;
        short8 hv, lv;
#pragma unroll
        for (int e = 0; e < 8; e++) {
            float wv = wp[(size_t)e * F_OUT];
            unsigned int hb = bf16_bits(wv);
            float hf = __uint_as_float(hb << 16);
            unsigned int lb = bf16_bits(wv - hf);
            hv[e] = (short)hb;
            lv[e] = (short)lb;
        }
        *(short8*)&sW[WHI(q, c, l)] = hv;
        *(short8*)&sW[WLO(q, c, l)] = lv;
    }
    __syncthreads();

    // per-lane attention weight slices (4 cols each, cached)
    float as4[4], ad4[4];
#pragma unroll
    for (int c = 0; c < 4; c++) {
        as4[c] = att_src[c * 16 + fr];
        ad4[c] = att_dst[c * 16 + fr];
    }

    const float4 z4 = make_float4(0.f, 0.f, 0.f, 0.f);

    for (int tile = blockIdx.x; tile < nTiles; tile += gridDim.x) {
        const int R0 = tile * 128 + w * 16;
        const int rowA = R0 + fr;
        const bool okA = rowA < N;
        const float* xrow = x + (size_t)rowA * F_IN + g * 8;

        f32x4 acc[4];
#pragma unroll
        for (int c = 0; c < 4; c++) acc[c] = (f32x4){0.f, 0.f, 0.f, 0.f};

        // depth-2 pipeline: only 4 float4 of x live at any time
        float4 cur0 = okA ? *(const float4*)(xrow + 0) : z4;
        float4 cur1 = okA ? *(const float4*)(xrow + 4) : z4;

#pragma unroll
        for (int q = 0; q < 8; q++) {
            float4 nxt0 = z4, nxt1 = z4;
            if (q < 7) {
                nxt0 = okA ? *(const float4*)(xrow + (q + 1) * 32)     : z4;
                nxt1 = okA ? *(const float4*)(xrow + (q + 1) * 32 + 4) : z4;
            }

            const float vf[8] = {cur0.x, cur0.y, cur0.z, cur0.w,
                                 cur1.x, cur1.y, cur1.z, cur1.w};
            short8 ahi, alo;
#pragma unroll
            for (int e = 0; e < 8; e++) {
                unsigned int hb = bf16_bits(vf[e]);
                float hf = __uint_as_float(hb << 16);
                unsigned int lb = bf16_bits(vf[e] - hf);
                ahi[e] = (short)hb;
                alo[e] = (short)lb;
            }
#pragma unroll
            for (int c = 0; c < 4; c++) {
                short8 bh = *(const short8*)&sW[WHI(q, c, lane)];
                short8 bl = *(const short8*)&sW[WLO(q, c, lane)];
                acc[c] = __builtin_amdgcn_mfma_f32_16x16x32_bf16(ahi, bh, acc[c], 0, 0, 0);
                acc[c] = __builtin_amdgcn_mfma_f32_16x16x32_bf16(alo, bh, acc[c], 0, 0, 0);
                acc[c] = __builtin_amdgcn_mfma_f32_16x16x32_bf16(ahi, bl, acc[c], 0, 0, 0);
            }
            cur0 = nxt0;
            cur1 = nxt1;
            __builtin_amdgcn_sched_barrier(0);   // pin pipeline depth (no re-hoist)
        }

        // ---- epilogue: a_src/a_dst partials ----
        float sr[4] = {0.f, 0.f, 0.f, 0.f};
        float sd[4] = {0.f, 0.f, 0.f, 0.f};
#pragma unroll
        for (int c = 0; c < 4; c++) {
#pragma unroll
            for (int r = 0; r < 4; r++) {
                float v = acc[c][r];
                sr[r] = fmaf(v, as4[c], sr[r]);
                sd[r] = fmaf(v, ad4[c], sd[r]);
            }
        }
#pragma unroll
        for (int off = 1; off <= 8; off <<= 1) {
#pragma unroll
            for (int r = 0; r < 4; r++) {
                sr[r] += __shfl_xor(sr[r], off, 64);
                sd[r] += __shfl_xor(sd[r], off, 64);
            }
        }

        // ---- h16 store: permuted layout, 8 B/lane, 4 full rows / instr ----
#pragma unroll
        for (int r = 0; r < 4; r++) {
            const int row = R0 + g * 4 + r;
            if (row < N) {
                unsigned int lo = bf16_bits(acc[0][r]) | (bf16_bits(acc[1][r]) << 16);
                unsigned int hi = bf16_bits(acc[2][r]) | (bf16_bits(acc[3][r]) << 16);
                *(int2*)(h16 + (size_t)row * F_OUT + fr * 4) = make_int2((int)lo, (int)hi);
            }
        }

        if (fr < 4) {
            const int row = R0 + g * 4 + fr;
            if (row < N) {
                float vs = (fr == 0) ? sr[0] : (fr == 1) ? sr[1] : (fr == 2) ? sr[2] : sr[3];
                float vd = (fr == 0) ? sd[0] : (fr == 1) ? sd[1] : (fr == 2) ? sd[2] : sd[3];
                a_src[row] = vs;
                a_dst[row] = vd;
            }
        }
    }
}

// ---------------------------------------------------------------------------
// Count: per-block LDS bucket histogram -> pbh[block][K] (no global atomics).
// ---------------------------------------------------------------------------
__global__ __launch_bounds__(1024) void bucket_count_kernel(
    const int* __restrict__ dst, int* __restrict__ pbh, int E, int K, int R)
{
    __shared__ int s[MAXK];
    const int t = threadIdx.x;
    for (int b = t; b < K; b += 1024) s[b] = 0;
    __syncthreads();
    const int start = blockIdx.x * R;
    const int end = min(E, start + R);
    for (int e = start + t * 4; e < end; e += 4096) {
        if (e + 3 < end) {
            int4 d = *(const int4*)&dst[e];
            atomicAdd(&s[d.x >> SHIFT], 1);
            atomicAdd(&s[d.y >> SHIFT], 1);
            atomicAdd(&s[d.z >> SHIFT], 1);
            atomicAdd(&s[d.w >> SHIFT], 1);
        } else {
            for (int q = e; q < end; q++) atomicAdd(&s[dst[q] >> SHIFT], 1);
        }
    }
    __syncthreads();
    int* row = pbh + (size_t)blockIdx.x * K;
    for (int b = t; b < K; b += 1024) row[b] = s[b];
}

// ---------------------------------------------------------------------------
// Column scan: one wave per bucket k. 64 lanes scan the 256 per-block counts
// in 4 chunks (wave shfl-scan + carry) -> cbase[block][k] (exclusive, base 0)
// and per-bucket total btot[k]. Fully parallel across 782 blocks.
// ---------------------------------------------------------------------------
__global__ __launch_bounds__(64) void colscan_kernel(
    const int* __restrict__ pbh, int* __restrict__ cbase,
    int* __restrict__ btot, int K, int NBLK)
{
    const int k = blockIdx.x;
    const int lane = threadIdx.x;
    // prefetch all chunks (NBLK <= 256 -> 4 chunks)
    int v[4];
#pragma unroll
    for (int c = 0; c < 4; c++) {
        int b = c * 64 + lane;
        v[c] = (b < NBLK) ? pbh[(size_t)b * K + k] : 0;
    }
    int carry = 0;
#pragma unroll
    for (int c = 0; c < 4; c++) {
        int orig = v[c];
        int s = v[c];
#pragma unroll
        for (int off = 1; off < 64; off <<= 1) {
            int u = __shfl_up(s, off, 64);
            if (lane >= off) s += u;
        }
        int b = c * 64 + lane;
        if (b < NBLK) cbase[(size_t)b * K + k] = carry + s - orig;  // exclusive
        carry += __shfl(s, 63, 64);
    }
    if (lane == 0) btot[k] = carry;
}

// ---------------------------------------------------------------------------
// Bucket base scan: exclusive scan of btot -> bbase (K <= 1024, one block).
// ---------------------------------------------------------------------------
__global__ __launch_bounds__(1024) void bbase_scan_kernel(
    const int* __restrict__ btot, int* __restrict__ bbase, int K, int E)
{
    __shared__ int s[1024];
    const int t = threadIdx.x;
    int v = (t < K) ? btot[t] : 0;
    s[t] = v;
    __syncthreads();
    for (int off = 1; off < 1024; off <<= 1) {
        int u = (t >= off) ? s[t - off] : 0;
        __syncthreads();
        s[t] += u;
        __syncthreads();
    }
    if (t < K) bbase[t] = s[t] - v;       // exclusive
    if (t == 0) bbase[K] = E;
}

// ---------------------------------------------------------------------------
// Bin: single sweep. LDS cursors = bbase[b] + this block's chunk base;
// per edge: one LDS atomic + one 4-B write into the block's ~50 KB window.
// Record = j | local_i << 17 (p recomputed in node_kernel).
// ---------------------------------------------------------------------------
__global__ __launch_bounds__(1024) void bin_kernel(
    const int* __restrict__ ei, const int* __restrict__ cbase,
    const int* __restrict__ bbase, int* __restrict__ rec, int E, int K, int R)
{
    __shared__ int cb[MAXK];
    const int t = threadIdx.x;
    const int start = blockIdx.x * R;
    const int end = min(E, start + R);
    const int* crow = cbase + (size_t)blockIdx.x * K;
    for (int b = t; b < K; b += 1024) cb[b] = bbase[b] + crow[b];
    __syncthreads();

    for (int e = start + t * 4; e < end; e += 4096) {
        if (e + 3 < end) {
            int4 jj = *(const int4*)&ei[e];
            int4 ii = *(const int4*)&ei[E + e];
            int p0 = atomicAdd(&cb[ii.x >> SHIFT], 1);
            int p1 = atomicAdd(&cb[ii.y >> SHIFT], 1);
            int p2 = atomicAdd(&cb[ii.z >> SHIFT], 1);
            int p3 = atomicAdd(&cb[ii.w >> SHIFT], 1);
            rec[p0] = jj.x | ((ii.x & (NPB - 1)) << 17);
            rec[p1] = jj.y | ((ii.y & (NPB - 1)) << 17);
            rec[p2] = jj.z | ((ii.z & (NPB - 1)) << 17);
            rec[p3] = jj.w | ((ii.w & (NPB - 1)) << 17);
        } else {
            for (int q = e; q < end; q++) {
                int j = ei[q], i = ei[E + q];
                int pos = atomicAdd(&cb[i >> SHIFT], 1);
                rec[pos] = j | ((i & (NPB - 1)) << 17);
            }
        }
    }
}

// ---------------------------------------------------------------------------
// Sort: one block per bucket; stage 4-B records in LDS (+overflow regs),
// count 128 local degrees, block-scan, in-place ordered write-back + row_ptr.
// ---------------------------------------------------------------------------
__global__ __launch_bounds__(256) void sort_kernel(
    int* __restrict__ rec, const int* __restrict__ bbase,
    int* __restrict__ row_ptr, int N, int E, int K)
{
    __shared__ int stage[CAP];
    __shared__ int deg[NPB];
    __shared__ int sval[NPB];
    __shared__ int base[NPB];
    __shared__ int cnt[NPB];
    const int t = threadIdx.x;
    const int b = blockIdx.x;
    const int s = bbase[b], e = bbase[b + 1];
    const int tot = e - s;
    const int nodeBase = b << SHIFT;
    const int nodes = min(NPB, N - nodeBase);

    if (t < NPB) deg[t] = 0;
    __syncthreads();

    int ovf[OVF];
    for (int r = t; r < tot; r += 256) {
        int m = rec[s + r];
        if (r < CAP) stage[r] = m;
        else { int k = (r - CAP) >> 8; if (k < OVF) ovf[k] = m; }
        atomicAdd(&deg[(m >> 17) & (NPB - 1)], 1);
    }
    __syncthreads();

    if (t < NPB) sval[t] = deg[t];
    __syncthreads();
    for (int off = 1; off < NPB; off <<= 1) {
        int v = (t < NPB && t >= off) ? sval[t - off] : 0;
        __syncthreads();
        if (t < NPB) sval[t] += v;
        __syncthreads();
    }
    if (t < NPB) {
        base[t] = sval[t] - deg[t];              // exclusive
        cnt[t] = 0;
        if (t < nodes) row_ptr[nodeBase + t] = s + base[t];
    }
    if (b == K - 1 && t == 0) row_ptr[N] = E;
    __syncthreads();

    for (int r = t; r < tot; r += 256) {
        int m = (r < CAP) ? stage[r] : ovf[(r - CAP) >> 8];
        int li = (m >> 17) & (NPB - 1);
        int rk = atomicAdd(&cnt[li], 1);
        rec[s + base[li] + rk] = m;              // 16-KB window, L2-combined
    }
}

// ---------------------------------------------------------------------------
// Node aggregation v3 (post-mortem R5: v2 latency-chain bound, ~2-deep MLP).
// Wide gathers: one instr fetches 4 ROWS (lane quarter q -> row j[4g+q],
// sub-lane a -> int2 = phys cols 4a..4a+3). 16 instrs / 64-edge chunk, ALL
// issued up-front into statically-indexed d[16] (32 VGPR, no runtime idx)
// -> ~17-deep MLP; p-compute waits only on the a_src gather (vmcnt order).
// Each lane accumulates 4 phys cols for its quarter's edges; two shfl_xor
// (16,32) combine quarters; lanes 0-15 add self-loop + bias, store 4x64-B
// coalesced dwords. h16 PERMUTED: phys 4a+c = logical c*16+a.
// ---------------------------------------------------------------------------
__global__ __launch_bounds__(256) void node_kernel(
    const __hip_bfloat16* __restrict__ h16, const float* __restrict__ a_src,
    const float* __restrict__ a_dst, const int* __restrict__ row_ptr,
    const int* __restrict__ rec, const float* __restrict__ bias,
    float* __restrict__ out, int N)
{
    const int w = threadIdx.x >> 6;
    const int lane = threadIdx.x & 63;
    const int i = blockIdx.x * 4 + w;
    if (i >= N) return;

    const int q = lane >> 4;        // row-quarter this lane serves in gathers
    const int a = lane & 15;        // int2 sub-index (phys cols 4a..4a+3)
    const unsigned short* __restrict__ hb = (const unsigned short*)h16;

    const int s = row_ptr[i];
    const int e = row_ptr[i + 1];

    const float adst_i = a_dst[i];
    float vs = a_src[i] + adst_i;
    vs = fmaxf(vs, NEG_SLOPE * vs);              // LeakyReLU(0.2)
    const float pself = __expf(vs);
    float denl = (lane == 0) ? pself : 0.f;

    float acc0 = 0.f, acc1 = 0.f, acc2 = 0.f, acc3 = 0.f;

    for (int k = s; k < e; k += 64) {
        const int cnt = min(64, e - k);
        int r = (lane < cnt) ? rec[k + lane] : 0;      // coalesced
        int j = r & 0x1FFFF;

        float asj = a_src[j];                          // scattered gather (A)

        // issue ALL 16 row-gathers (4 rows / instr) before waiting on A
        int2 d[16];
#pragma unroll
        for (int g = 0; g < 16; g++) {
            int jsel = __shfl(j, 4 * g + q, 64);
            d[g] = *(const int2*)(hb + (size_t)jsel * F_OUT + a * 4);
        }

        // p-compute (vmcnt retires a_src first; d[] stays in flight)
        float v = asj + adst_i;
        v = fmaxf(v, NEG_SLOPE * v);
        float p = __expf(v);                           // ONE exp / 64 edges
        if (lane >= cnt) p = 0.f;
        denl += p;

        // consume: unpack + 4 fma per 4-row group
#pragma unroll
        for (int g = 0; g < 16; g++) {
            float psel = __shfl(p, 4 * g + q, 64);
            unsigned int lo = (unsigned int)d[g].x;
            unsigned int hi = (unsigned int)d[g].y;
            acc0 = fmaf(psel, __uint_as_float(lo << 16), acc0);
            acc1 = fmaf(psel, __uint_as_float(lo & 0xFFFF0000u), acc1);
            acc2 = fmaf(psel, __uint_as_float(hi << 16), acc2);
            acc3 = fmaf(psel, __uint_as_float(hi & 0xFFFF0000u), acc3);
        }
    }

    // combine the 4 quarters (every lane ends with the full column sums)
#pragma unroll
    for (int o = 16; o <= 32; o <<= 1) {
        acc0 += __shfl_xor(acc0, o, 64);
        acc1 += __shfl_xor(acc1, o, 64);
        acc2 += __shfl_xor(acc2, o, 64);
        acc3 += __shfl_xor(acc3, o, 64);
    }
    float den = denl;
#pragma unroll
    for (int o = 32; o > 0; o >>= 1) den += __shfl_xor(den, o, 64);
    den += 1e-16f;

    if (lane < 16) {
        // self-loop term + bias + store (4 x 64-B coalesced dword stores)
        int2 hs = *(const int2*)(hb + (size_t)i * F_OUT + a * 4);
        unsigned int lo = (unsigned int)hs.x, hi = (unsigned int)hs.y;
        float s0 = acc0 + pself * __uint_as_float(lo << 16);
        float s1 = acc1 + pself * __uint_as_float(lo & 0xFFFF0000u);
        float s2 = acc2 + pself * __uint_as_float(hi << 16);
        float s3 = acc3 + pself * __uint_as_float(hi & 0xFFFF0000u);
        float* orow = out + (size_t)i * F_OUT;
        orow[ 0 + a] = s0 / den + bias[ 0 + a];
        orow[16 + a] = s1 / den + bias[16 + a];
        orow[32 + a] = s2 / den + bias[32 + a];
        orow[48 + a] = s3 / den + bias[48 + a];
    }
}

// ---------------------------------------------------------------------------
extern "C" void kernel_launch(void* const* d_in, const int* in_sizes, int n_in,
                              void* d_out, int out_size, void* d_ws, size_t ws_size,
                              hipStream_t stream)
{
    const float* x      = (const float*)d_in[0];
    const int*   ei     = (const int*)d_in[1];
    const float* W      = (const float*)d_in[2];
    const float* att_sr = (const float*)d_in[3];
    const float* att_ds = (const float*)d_in[4];
    const float* bias   = (const float*)d_in[5];
    float* out = (float*)d_out;

    const int N = in_sizes[0] / F_IN;
    const int E = in_sizes[1] / 2;
    const int K = (N + NPB - 1) >> SHIFT;   // 782 for N=100000
    const int R = (((E + GRID_B - 1) / GRID_B) + 3) & ~3;   // per-block range, x4

    char* ws = (char*)d_ws;
    size_t off = 0;
    auto alloc = [&](size_t bytes) -> void* {
        void* p = ws + off;
        off = (off + bytes + 255) & ~(size_t)255;
        return p;
    };
    __hip_bfloat16* h16 = (__hip_bfloat16*)alloc((size_t)N * F_OUT * 2);
    float* a_src   = (float*)alloc((size_t)N * 4);
    float* a_dst   = (float*)alloc((size_t)N * 4);
    int*   pbh     = (int*)alloc((size_t)GRID_B * K * 4);
    int*   cbase   = (int*)alloc((size_t)GRID_B * K * 4);
    int*   btot    = (int*)alloc((size_t)K * 4);
    int*   bbase   = (int*)alloc((size_t)(K + 1) * 4);
    int*   row_ptr = (int*)alloc((size_t)(N + 1) * 4);
    int*   rec     = (int*)alloc((size_t)E * 4);
    (void)ws_size; (void)n_in; (void)out_size;

    const int nTiles = (N + 127) >> 7;                      // 128-row tiles
    const int gemmGrid = nTiles < 512 ? nTiles : 512;       // 2 blocks/CU

    gemm_kernel<<<gemmGrid, 512, 0, stream>>>(x, W, att_sr, att_ds, h16, a_src, a_dst, N, nTiles);
    bucket_count_kernel<<<GRID_B, 1024, 0, stream>>>(ei + E, pbh, E, K, R);
    colscan_kernel<<<K, 64, 0, stream>>>(pbh, cbase, btot, K, GRID_B);
    bbase_scan_kernel<<<1, 1024, 0, stream>>>(btot, bbase, K, E);
    bin_kernel<<<GRID_B, 1024, 0, stream>>>(ei, cbase, bbase, rec, E, K, R);
    sort_kernel<<<K, 256, 0, stream>>>(rec, bbase, row_ptr, N, E, K);
    node_kernel<<<(N + 3) / 4, 256, 0, stream>>>(h16, a_src, a_dst, row_ptr, rec, bias, out, N);
}

// Round 7
// 318.900 us; speedup vs baseline: 1.1925x; 1.0385x over previous
//
#include <hip/hip_runtime.h>
#include <hip/hip_bf16.h>
#include <math.h>

#define F_IN 256
#define F_OUT 64
#define NEG_SLOPE 0.2f
#define SHIFT 7
#define NPB 128            // nodes per bucket
#define MAXK 1024          // max buckets (N <= 131072, matches 17-bit j pack)
#define CAP 4608           // LDS staging records/bucket (mean 4096, +8 sigma)
#define OVF 4              // per-thread overflow regs (+1024 records headroom)
#define GRID_B 256         // blocks for count/bin (ranges must match)

__device__ __forceinline__ float bf2f(__hip_bfloat16 v) {
    return __bfloat162float(v);
}

typedef short short8 __attribute__((ext_vector_type(8)));
typedef float f32x4 __attribute__((ext_vector_type(4)));

// RNE float->bf16 bits (finite inputs)
__device__ __forceinline__ unsigned int bf16_bits(float v) {
    unsigned int u = __float_as_uint(v);
    return (u + 0x7fffu + ((u >> 16) & 1u)) >> 16;
}

// ---------------------------------------------------------------------------
// MFMA GEMM: h16 = bf16(x @ W) [PERMUTED layout], a_src = h@att_src,
// a_dst = h@att_dst.  bf16x3 split (xh*Wh + xl*Wh + xh*Wl) ~ fp32 accuracy.
//
// v4 (verified R4): depth-2 software pipeline in q (only cur/nxt float4 pairs
// live, sched_barrier(0) pins it) -> no scratch spill. (512,2): 16 waves/CU,
// VGPR 128, LDS 64 KB. h16 stored PERMUTED (phys fr*4+c = logical c*16+fr):
// 8-B/lane stores, 4 full 128-B rows per instruction.
// ---------------------------------------------------------------------------
#define WHI(q, c, l) (((((q)*4 + (c)) * 64) + (l)) * 8)
#define WLO(q, c, l) (16384 + WHI(q, c, l))

__global__ __launch_bounds__(512, 2) void gemm_kernel(
    const float* __restrict__ x, const float* __restrict__ W,
    const float* __restrict__ att_src, const float* __restrict__ att_dst,
    __hip_bfloat16* __restrict__ h16, float* __restrict__ a_src,
    float* __restrict__ a_dst, int N, int nTiles)
{
    __shared__ unsigned short sW[32768];   // [hi|lo][q][c][lane][e] = 64 KB

    const int t = threadIdx.x;
    const int lane = t & 63;
    const int w = t >> 6;          // wave id (0..7)
    const int g = lane >> 4;       // k-block group (0..3)
    const int fr = lane & 15;      // A-row / B-col / D-col within fragment

    // ---- stage W as hi/lo bf16 fragments (once per block) ----
    for (int idx = t; idx < 2048; idx += 512) {
        const int q = idx >> 8;
        const int c = (idx >> 6) & 3;
        const int l = idx & 63;
        const int col = c * 16 + (l & 15);
        const float* wp = W + (size_t)(q * 32 + ((l >> 4) * 8)) * F_OUT + col;
        short8 hv, lv;
#pragma unroll
        for (int e = 0; e < 8; e++) {
            float wv = wp[(size_t)e * F_OUT];
            unsigned int hb = bf16_bits(wv);
            float hf = __uint_as_float(hb << 16);
            unsigned int lb = bf16_bits(wv - hf);
            hv[e] = (short)hb;
            lv[e] = (short)lb;
        }
        *(short8*)&sW[WHI(q, c, l)] = hv;
        *(short8*)&sW[WLO(q, c, l)] = lv;
    }
    __syncthreads();

    // per-lane attention weight slices (4 cols each, cached)
    float as4[4], ad4[4];
#pragma unroll
    for (int c = 0; c < 4; c++) {
        as4[c] = att_src[c * 16 + fr];
        ad4[c] = att_dst[c * 16 + fr];
    }

    const float4 z4 = make_float4(0.f, 0.f, 0.f, 0.f);

    for (int tile = blockIdx.x; tile < nTiles; tile += gridDim.x) {
        const int R0 = tile * 128 + w * 16;
        const int rowA = R0 + fr;
        const bool okA = rowA < N;
        const float* xrow = x + (size_t)rowA * F_IN + g * 8;

        f32x4 acc[4];
#pragma unroll
        for (int c = 0; c < 4; c++) acc[c] = (f32x4){0.f, 0.f, 0.f, 0.f};

        // depth-2 pipeline: only 4 float4 of x live at any time
        float4 cur0 = okA ? *(const float4*)(xrow + 0) : z4;
        float4 cur1 = okA ? *(const float4*)(xrow + 4) : z4;

#pragma unroll
        for (int q = 0; q < 8; q++) {
            float4 nxt0 = z4, nxt1 = z4;
            if (q < 7) {
                nxt0 = okA ? *(const float4*)(xrow + (q + 1) * 32)     : z4;
                nxt1 = okA ? *(const float4*)(xrow + (q + 1) * 32 + 4) : z4;
            }

            const float vf[8] = {cur0.x, cur0.y, cur0.z, cur0.w,
                                 cur1.x, cur1.y, cur1.z, cur1.w};
            short8 ahi, alo;
#pragma unroll
            for (int e = 0; e < 8; e++) {
                unsigned int hb = bf16_bits(vf[e]);
                float hf = __uint_as_float(hb << 16);
                unsigned int lb = bf16_bits(vf[e] - hf);
                ahi[e] = (short)hb;
                alo[e] = (short)lb;
            }
#pragma unroll
            for (int c = 0; c < 4; c++) {
                short8 bh = *(const short8*)&sW[WHI(q, c, lane)];
                short8 bl = *(const short8*)&sW[WLO(q, c, lane)];
                acc[c] = __builtin_amdgcn_mfma_f32_16x16x32_bf16(ahi, bh, acc[c], 0, 0, 0);
                acc[c] = __builtin_amdgcn_mfma_f32_16x16x32_bf16(alo, bh, acc[c], 0, 0, 0);
                acc[c] = __builtin_amdgcn_mfma_f32_16x16x32_bf16(ahi, bl, acc[c], 0, 0, 0);
            }
            cur0 = nxt0;
            cur1 = nxt1;
            __builtin_amdgcn_sched_barrier(0);   // pin pipeline depth (no re-hoist)
        }

        // ---- epilogue: a_src/a_dst partials ----
        float sr[4] = {0.f, 0.f, 0.f, 0.f};
        float sd[4] = {0.f, 0.f, 0.f, 0.f};
#pragma unroll
        for (int c = 0; c < 4; c++) {
#pragma unroll
            for (int r = 0; r < 4; r++) {
                float v = acc[c][r];
                sr[r] = fmaf(v, as4[c], sr[r]);
                sd[r] = fmaf(v, ad4[c], sd[r]);
            }
        }
#pragma unroll
        for (int off = 1; off <= 8; off <<= 1) {
#pragma unroll
            for (int r = 0; r < 4; r++) {
                sr[r] += __shfl_xor(sr[r], off, 64);
                sd[r] += __shfl_xor(sd[r], off, 64);
            }
        }

        // ---- h16 store: permuted layout, 8 B/lane, 4 full rows / instr ----
#pragma unroll
        for (int r = 0; r < 4; r++) {
            const int row = R0 + g * 4 + r;
            if (row < N) {
                unsigned int lo = bf16_bits(acc[0][r]) | (bf16_bits(acc[1][r]) << 16);
                unsigned int hi = bf16_bits(acc[2][r]) | (bf16_bits(acc[3][r]) << 16);
                *(int2*)(h16 + (size_t)row * F_OUT + fr * 4) = make_int2((int)lo, (int)hi);
            }
        }

        if (fr < 4) {
            const int row = R0 + g * 4 + fr;
            if (row < N) {
                float vs = (fr == 0) ? sr[0] : (fr == 1) ? sr[1] : (fr == 2) ? sr[2] : sr[3];
                float vd = (fr == 0) ? sd[0] : (fr == 1) ? sd[1] : (fr == 2) ? sd[2] : sd[3];
                a_src[row] = vs;
                a_dst[row] = vd;
            }
        }
    }
}

// ---------------------------------------------------------------------------
// Count: per-block LDS bucket histogram -> pbh[block][K] (no global atomics).
// ---------------------------------------------------------------------------
__global__ __launch_bounds__(1024) void bucket_count_kernel(
    const int* __restrict__ dst, int* __restrict__ pbh, int E, int K, int R)
{
    __shared__ int s[MAXK];
    const int t = threadIdx.x;
    for (int b = t; b < K; b += 1024) s[b] = 0;
    __syncthreads();
    const int start = blockIdx.x * R;
    const int end = min(E, start + R);
    for (int e = start + t * 4; e < end; e += 4096) {
        if (e + 3 < end) {
            int4 d = *(const int4*)&dst[e];
            atomicAdd(&s[d.x >> SHIFT], 1);
            atomicAdd(&s[d.y >> SHIFT], 1);
            atomicAdd(&s[d.z >> SHIFT], 1);
            atomicAdd(&s[d.w >> SHIFT], 1);
        } else {
            for (int q = e; q < end; q++) atomicAdd(&s[dst[q] >> SHIFT], 1);
        }
    }
    __syncthreads();
    int* row = pbh + (size_t)blockIdx.x * K;
    for (int b = t; b < K; b += 1024) row[b] = s[b];
}

// ---------------------------------------------------------------------------
// Column scan: one wave per bucket k. 64 lanes scan the 256 per-block counts
// in 4 chunks (wave shfl-scan + carry) -> cbase[block][k] (exclusive, base 0)
// and per-bucket total btot[k]. Fully parallel across 782 blocks.
// ---------------------------------------------------------------------------
__global__ __launch_bounds__(64) void colscan_kernel(
    const int* __restrict__ pbh, int* __restrict__ cbase,
    int* __restrict__ btot, int K, int NBLK)
{
    const int k = blockIdx.x;
    const int lane = threadIdx.x;
    // prefetch all chunks (NBLK <= 256 -> 4 chunks)
    int v[4];
#pragma unroll
    for (int c = 0; c < 4; c++) {
        int b = c * 64 + lane;
        v[c] = (b < NBLK) ? pbh[(size_t)b * K + k] : 0;
    }
    int carry = 0;
#pragma unroll
    for (int c = 0; c < 4; c++) {
        int orig = v[c];
        int s = v[c];
#pragma unroll
        for (int off = 1; off < 64; off <<= 1) {
            int u = __shfl_up(s, off, 64);
            if (lane >= off) s += u;
        }
        int b = c * 64 + lane;
        if (b < NBLK) cbase[(size_t)b * K + k] = carry + s - orig;  // exclusive
        carry += __shfl(s, 63, 64);
    }
    if (lane == 0) btot[k] = carry;
}

// ---------------------------------------------------------------------------
// Bucket base scan: exclusive scan of btot -> bbase (K <= 1024, one block).
// ---------------------------------------------------------------------------
__global__ __launch_bounds__(1024) void bbase_scan_kernel(
    const int* __restrict__ btot, int* __restrict__ bbase, int K, int E)
{
    __shared__ int s[1024];
    const int t = threadIdx.x;
    int v = (t < K) ? btot[t] : 0;
    s[t] = v;
    __syncthreads();
    for (int off = 1; off < 1024; off <<= 1) {
        int u = (t >= off) ? s[t - off] : 0;
        __syncthreads();
        s[t] += u;
        __syncthreads();
    }
    if (t < K) bbase[t] = s[t] - v;       // exclusive
    if (t == 0) bbase[K] = E;
}

// ---------------------------------------------------------------------------
// Bin: single sweep. LDS cursors = bbase[b] + this block's chunk base;
// per edge: one LDS atomic + one 4-B write into the block's ~50 KB window.
// Record = j | local_i << 17 (p recomputed in node_kernel).
// ---------------------------------------------------------------------------
__global__ __launch_bounds__(1024) void bin_kernel(
    const int* __restrict__ ei, const int* __restrict__ cbase,
    const int* __restrict__ bbase, int* __restrict__ rec, int E, int K, int R)
{
    __shared__ int cb[MAXK];
    const int t = threadIdx.x;
    const int start = blockIdx.x * R;
    const int end = min(E, start + R);
    const int* crow = cbase + (size_t)blockIdx.x * K;
    for (int b = t; b < K; b += 1024) cb[b] = bbase[b] + crow[b];
    __syncthreads();

    for (int e = start + t * 4; e < end; e += 4096) {
        if (e + 3 < end) {
            int4 jj = *(const int4*)&ei[e];
            int4 ii = *(const int4*)&ei[E + e];
            int p0 = atomicAdd(&cb[ii.x >> SHIFT], 1);
            int p1 = atomicAdd(&cb[ii.y >> SHIFT], 1);
            int p2 = atomicAdd(&cb[ii.z >> SHIFT], 1);
            int p3 = atomicAdd(&cb[ii.w >> SHIFT], 1);
            rec[p0] = jj.x | ((ii.x & (NPB - 1)) << 17);
            rec[p1] = jj.y | ((ii.y & (NPB - 1)) << 17);
            rec[p2] = jj.z | ((ii.z & (NPB - 1)) << 17);
            rec[p3] = jj.w | ((ii.w & (NPB - 1)) << 17);
        } else {
            for (int q = e; q < end; q++) {
                int j = ei[q], i = ei[E + q];
                int pos = atomicAdd(&cb[i >> SHIFT], 1);
                rec[pos] = j | ((i & (NPB - 1)) << 17);
            }
        }
    }
}

// ---------------------------------------------------------------------------
// Sort: one block per bucket; stage 4-B records in LDS (+overflow regs),
// count 128 local degrees, block-scan, in-place ordered write-back + row_ptr.
// ---------------------------------------------------------------------------
__global__ __launch_bounds__(256) void sort_kernel(
    int* __restrict__ rec, const int* __restrict__ bbase,
    int* __restrict__ row_ptr, int N, int E, int K)
{
    __shared__ int stage[CAP];
    __shared__ int deg[NPB];
    __shared__ int sval[NPB];
    __shared__ int base[NPB];
    __shared__ int cnt[NPB];
    const int t = threadIdx.x;
    const int b = blockIdx.x;
    const int s = bbase[b], e = bbase[b + 1];
    const int tot = e - s;
    const int nodeBase = b << SHIFT;
    const int nodes = min(NPB, N - nodeBase);

    if (t < NPB) deg[t] = 0;
    __syncthreads();

    int ovf[OVF];
    for (int r = t; r < tot; r += 256) {
        int m = rec[s + r];
        if (r < CAP) stage[r] = m;
        else { int k = (r - CAP) >> 8; if (k < OVF) ovf[k] = m; }
        atomicAdd(&deg[(m >> 17) & (NPB - 1)], 1);
    }
    __syncthreads();

    if (t < NPB) sval[t] = deg[t];
    __syncthreads();
    for (int off = 1; off < NPB; off <<= 1) {
        int v = (t < NPB && t >= off) ? sval[t - off] : 0;
        __syncthreads();
        if (t < NPB) sval[t] += v;
        __syncthreads();
    }
    if (t < NPB) {
        base[t] = sval[t] - deg[t];              // exclusive
        cnt[t] = 0;
        if (t < nodes) row_ptr[nodeBase + t] = s + base[t];
    }
    if (b == K - 1 && t == 0) row_ptr[N] = E;
    __syncthreads();

    for (int r = t; r < tot; r += 256) {
        int m = (r < CAP) ? stage[r] : ovf[(r - CAP) >> 8];
        int li = (m >> 17) & (NPB - 1);
        int rk = atomicAdd(&cnt[li], 1);
        rec[s + base[li] + rk] = m;              // 16-KB window, L2-combined
    }
}

// ---------------------------------------------------------------------------
// Node aggregation v4 (post-mortem R6: instruction-issue bound; ~45% of
// chunk work was p=0 padding for mean degree 33, plus 2 bpermutes/group).
//  - Dynamic group bound G = ceil(cnt/4): unrolled 16x with wave-uniform
//    guard (d[16] stays statically indexed -> registers, no scratch).
//  - j/p broadcast via 2 KB LDS: written once per chunk, read per group
//    with ds_read at immediate offset (quarter lanes share an address ->
//    LDS broadcast, zero per-group address math). sched_barrier(0) pins
//    same-wave write->read order.
// Wide gathers unchanged: 4 rows/instr (quarter q -> row j[4g+q], sub-lane
// a -> int2 phys cols 4a..4a+3), all issued before p-compute waits.
// h16 PERMUTED: phys 4a+c = logical c*16+a.
// ---------------------------------------------------------------------------
__global__ __launch_bounds__(256) void node_kernel(
    const __hip_bfloat16* __restrict__ h16, const float* __restrict__ a_src,
    const float* __restrict__ a_dst, const int* __restrict__ row_ptr,
    const int* __restrict__ rec, const float* __restrict__ bias,
    float* __restrict__ out, int N)
{
    __shared__ int   sj[4][64];
    __shared__ float sp[4][64];

    const int w = threadIdx.x >> 6;
    const int lane = threadIdx.x & 63;
    const int i = blockIdx.x * 4 + w;
    if (i >= N) return;

    const int q = lane >> 4;        // row-quarter this lane serves in gathers
    const int a = lane & 15;        // int2 sub-index (phys cols 4a..4a+3)
    const unsigned short* __restrict__ hb = (const unsigned short*)h16;
    const unsigned short* __restrict__ hba = hb + a * 4;

    int*   sjw = &sj[w][0];
    float* spw = &sp[w][0];
    const int*   sjq = &sj[w][q];   // per-lane read base (offset 16g bytes/4)
    const float* spq = &sp[w][q];

    const int s = row_ptr[i];
    const int e = row_ptr[i + 1];

    const float adst_i = a_dst[i];
    float vs = a_src[i] + adst_i;
    vs = fmaxf(vs, NEG_SLOPE * vs);              // LeakyReLU(0.2)
    const float pself = __expf(vs);
    float denl = (lane == 0) ? pself : 0.f;

    float acc0 = 0.f, acc1 = 0.f, acc2 = 0.f, acc3 = 0.f;

    for (int k = s; k < e; k += 64) {
        const int cnt = min(64, e - k);          // wave-uniform
        const int G = (cnt + 3) >> 2;            // active 4-row groups
        int r = (lane < cnt) ? rec[k + lane] : 0;      // coalesced
        int j = r & 0x1FFFF;
        sjw[lane] = j;

        float asj = a_src[j];                          // scattered gather (A)
        __builtin_amdgcn_sched_barrier(0);             // j visible before reads

        // issue the G row-gathers (4 rows / instr) before waiting on A
        int2 d[16];
#pragma unroll
        for (int g = 0; g < 16; g++) {
            if (g < G) {
                int jsel = sjq[4 * g];                 // ds_read, imm offset
                d[g] = *(const int2*)(hba + (size_t)jsel * F_OUT);
            }
        }

        // p-compute (vmcnt retires a_src first; d[] stays in flight)
        float v = asj + adst_i;
        v = fmaxf(v, NEG_SLOPE * v);
        float p = __expf(v);                           // ONE exp / 64 edges
        if (lane >= cnt) p = 0.f;
        denl += p;
        spw[lane] = p;
        __builtin_amdgcn_sched_barrier(0);             // p visible before reads

        // consume: psel from LDS, unpack + 4 fma per active group
#pragma unroll
        for (int g = 0; g < 16; g++) {
            if (g < G) {
                float psel = spq[4 * g];               // ds_read, imm offset
                unsigned int lo = (unsigned int)d[g].x;
                unsigned int hi = (unsigned int)d[g].y;
                acc0 = fmaf(psel, __uint_as_float(lo << 16), acc0);
                acc1 = fmaf(psel, __uint_as_float(lo & 0xFFFF0000u), acc1);
                acc2 = fmaf(psel, __uint_as_float(hi << 16), acc2);
                acc3 = fmaf(psel, __uint_as_float(hi & 0xFFFF0000u), acc3);
            }
        }
        __builtin_amdgcn_sched_barrier(0);             // protect sj/sp reuse
    }

    // combine the 4 quarters (every lane ends with the full column sums)
#pragma unroll
    for (int o = 16; o <= 32; o <<= 1) {
        acc0 += __shfl_xor(acc0, o, 64);
        acc1 += __shfl_xor(acc1, o, 64);
        acc2 += __shfl_xor(acc2, o, 64);
        acc3 += __shfl_xor(acc3, o, 64);
    }
    float den = denl;
#pragma unroll
    for (int o = 32; o > 0; o >>= 1) den += __shfl_xor(den, o, 64);
    den += 1e-16f;

    if (lane < 16) {
        // self-loop term + bias + store (4 x 64-B coalesced dword stores)
        int2 hs = *(const int2*)(hb + (size_t)i * F_OUT + a * 4);
        unsigned int lo = (unsigned int)hs.x, hi = (unsigned int)hs.y;
        float s0 = acc0 + pself * __uint_as_float(lo << 16);
        float s1 = acc1 + pself * __uint_as_float(lo & 0xFFFF0000u);
        float s2 = acc2 + pself * __uint_as_float(hi << 16);
        float s3 = acc3 + pself * __uint_as_float(hi & 0xFFFF0000u);
        float* orow = out + (size_t)i * F_OUT;
        orow[ 0 + a] = s0 / den + bias[ 0 + a];
        orow[16 + a] = s1 / den + bias[16 + a];
        orow[32 + a] = s2 / den + bias[32 + a];
        orow[48 + a] = s3 / den + bias[48 + a];
    }
}

// ---------------------------------------------------------------------------
extern "C" void kernel_launch(void* const* d_in, const int* in_sizes, int n_in,
                              void* d_out, int out_size, void* d_ws, size_t ws_size,
                              hipStream_t stream)
{
    const float* x      = (const float*)d_in[0];
    const int*   ei     = (const int*)d_in[1];
    const float* W      = (const float*)d_in[2];
    const float* att_sr = (const float*)d_in[3];
    const float* att_ds = (const float*)d_in[4];
    const float* bias   = (const float*)d_in[5];
    float* out = (float*)d_out;

    const int N = in_sizes[0] / F_IN;
    const int E = in_sizes[1] / 2;
    const int K = (N + NPB - 1) >> SHIFT;   // 782 for N=100000
    const int R = (((E + GRID_B - 1) / GRID_B) + 3) & ~3;   // per-block range, x4

    char* ws = (char*)d_ws;
    size_t off = 0;
    auto alloc = [&](size_t bytes) -> void* {
        void* p = ws + off;
        off = (off + bytes + 255) & ~(size_t)255;
        return p;
    };
    __hip_bfloat16* h16 = (__hip_bfloat16*)alloc((size_t)N * F_OUT * 2);
    float* a_src   = (float*)alloc((size_t)N * 4);
    float* a_dst   = (float*)alloc((size_t)N * 4);
    int*   pbh     = (int*)alloc((size_t)GRID_B * K * 4);
    int*   cbase   = (int*)alloc((size_t)GRID_B * K * 4);
    int*   btot    = (int*)alloc((size_t)K * 4);
    int*   bbase   = (int*)alloc((size_t)(K + 1) * 4);
    int*   row_ptr = (int*)alloc((size_t)(N + 1) * 4);
    int*   rec     = (int*)alloc((size_t)E * 4);
    (void)ws_size; (void)n_in; (void)out_size;

    const int nTiles = (N + 127) >> 7;                      // 128-row tiles
    const int gemmGrid = nTiles < 512 ? nTiles : 512;       // 2 blocks/CU

    gemm_kernel<<<gemmGrid, 512, 0, stream>>>(x, W, att_sr, att_ds, h16, a_src, a_dst, N, nTiles);
    bucket_count_kernel<<<GRID_B, 1024, 0, stream>>>(ei + E, pbh, E, K, R);
    colscan_kernel<<<K, 64, 0, stream>>>(pbh, cbase, btot, K, GRID_B);
    bbase_scan_kernel<<<1, 1024, 0, stream>>>(btot, bbase, K, E);
    bin_kernel<<<GRID_B, 1024, 0, stream>>>(ei, cbase, bbase, rec, E, K, R);
    sort_kernel<<<K, 256, 0, stream>>>(rec, bbase, row_ptr, N, E, K);
    node_kernel<<<(N + 3) / 4, 256, 0, stream>>>(h16, a_src, a_dst, row_ptr, rec, bias, out, N);
}